// Round 2
// baseline (467.062 us; speedup 1.0000x reference)
//
#include <hip/hip_runtime.h>

#define Bc 2
#define Gc 8
#define Dc 32
#define Hc 128
#define Wc 160
#define HW (Hc * Wc)         // 20480
#define DHW (Dc * HW)        // 655360

// Fused tiling: one block = one (b, d, 32x40 output tile).
// sim computed with reflect halo R=4 into LDS, aggregation reads LDS only.
#define TH 32
#define TW 40
#define R  4
#define SH (TH + 2 * R)      // 40
#define SW (TW + 2 * R)      // 48
#define SIMN (SH * SW)       // 1920
#define NQ (SIMN / 4)        // 480 float4-quads
#define QPR (SW / 4)         // 12 quads per sim-tile row

// (256,3): 3 waves/EU min -> VGPR cap ~170. Round-1 failure mode was the
// compiler unrolling the q-loop x2 -> 256 VGPR -> 400 MB scratch spill.
__global__ __launch_bounds__(256, 3) void fused_kernel(
    const float* __restrict__ x1, const float* __restrict__ offset,
    const float* __restrict__ weight,
    const float* __restrict__ w0, const float* __restrict__ s0, const float* __restrict__ b0,
    const float* __restrict__ w1, const float* __restrict__ s1, const float* __restrict__ b1,
    const float* __restrict__ wsim, const float* __restrict__ bsim,
    float* __restrict__ out)
{
    __shared__ __align__(16) float sms[SIMN];  // sim tile with halo
    __shared__ float smw[289];                 // folded MLP weights
    const int tid = threadIdx.x;

    // stage BN-folded weights
    for (int i = tid; i < 289; i += 256) {
        float v;
        if (i < 128)      v = w0[i] * s0[i >> 3];                 // w0f[o][g]
        else if (i < 144) v = b0[i - 128];
        else if (i < 272) v = w1[i - 144] * s1[(i - 144) >> 4];   // w1f[c][o]
        else if (i < 280) v = b1[i - 272];
        else if (i < 288) v = wsim[i - 280];
        else              v = bsim[0];
        smw[i] = v;
    }

    // blk = b*512 + tile*32 + d  (d innermost: consecutive blocks share the
    // offset/weight tile in L2; tile-neighbors are +32/+128 blocks = same XCD)
    const int blk = blockIdx.x;              // 1024 blocks
    const int d   = blk & 31;
    const int t   = (blk >> 5) & 15;
    const int b   = blk >> 9;
    const int h0t = (t >> 2) * TH;
    const int w0t = (t & 3) * TW;

    __syncthreads();

    const float* sw0 = smw;
    const float* sb0 = smw + 128;
    const float* sw1 = smw + 144;
    const float* sb1 = smw + 272;
    const float* sws = smw + 280;
    const float  sbs = smw[288];

    const float* xb = x1 + (size_t)b * (Gc * DHW) + (size_t)d * HW;

    // ---- phase 1: MLP 8->16->8->1 into the LDS sim tile (incl. reflect halo)
    // unroll 1: exactly ONE live copy of xv[8]+h0[16] (~96 VGPR), no spill.
#pragma unroll 1
    for (int q = tid; q < NQ; q += 256) {
        const int ty  = q / QPR;
        const int tx0 = (q - ty * QPR) * 4;
        int gh = h0t - R + ty;
        gh = gh < 0 ? -gh : (gh >= Hc ? 2 * Hc - 2 - gh : gh);
        const int gw0 = w0t - R + tx0;

        float4 xv[Gc];
        if (gw0 >= 0 && gw0 <= Wc - 4) {
            // fast path: contiguous, 16B-aligned (w0t,tx0 multiples of 4)
            const float* p = xb + gh * Wc + gw0;
#pragma unroll
            for (int g = 0; g < Gc; ++g)
                xv[g] = *reinterpret_cast<const float4*>(p + g * DHW);
        } else {
            // reflected (reversed) edge quad: 4 scalar gathers per g
            int gw[4];
#pragma unroll
            for (int j = 0; j < 4; ++j) {
                int x = gw0 + j;
                gw[j] = x < 0 ? -x : (x >= Wc ? 2 * Wc - 2 - x : x);
            }
            const float* p = xb + gh * Wc;
#pragma unroll
            for (int g = 0; g < Gc; ++g) {
                xv[g].x = p[g * DHW + gw[0]];
                xv[g].y = p[g * DHW + gw[1]];
                xv[g].z = p[g * DHW + gw[2]];
                xv[g].w = p[g * DHW + gw[3]];
            }
        }

        // layer 0: 8 -> 16, relu
        float4 h0[16];
#pragma unroll
        for (int o = 0; o < 16; ++o) {
            float ax = sb0[o], ay = ax, az = ax, aw = ax;
#pragma unroll
            for (int g = 0; g < Gc; ++g) {
                const float wv = sw0[o * Gc + g];
                ax = fmaf(wv, xv[g].x, ax);
                ay = fmaf(wv, xv[g].y, ay);
                az = fmaf(wv, xv[g].z, az);
                aw = fmaf(wv, xv[g].w, aw);
            }
            h0[o].x = fmaxf(ax, 0.f);
            h0[o].y = fmaxf(ay, 0.f);
            h0[o].z = fmaxf(az, 0.f);
            h0[o].w = fmaxf(aw, 0.f);
        }

        // layer 1: 16 -> 8, relu; fused sim projection 8 -> 1
        float sx = sbs, sy = sbs, sz = sbs, sw = sbs;
#pragma unroll
        for (int c = 0; c < 8; ++c) {
            float ax = sb1[c], ay = ax, az = ax, aw = ax;
#pragma unroll
            for (int o = 0; o < 16; ++o) {
                const float wv = sw1[c * 16 + o];
                ax = fmaf(wv, h0[o].x, ax);
                ay = fmaf(wv, h0[o].y, ay);
                az = fmaf(wv, h0[o].z, az);
                aw = fmaf(wv, h0[o].w, aw);
            }
            const float ws = sws[c];
            sx = fmaf(ws, fmaxf(ax, 0.f), sx);
            sy = fmaf(ws, fmaxf(ay, 0.f), sy);
            sz = fmaf(ws, fmaxf(az, 0.f), sz);
            sw = fmaf(ws, fmaxf(aw, 0.f), sw);
        }

        float4 r; r.x = sx; r.y = sy; r.z = sz; r.w = sw;
        // q*4 == ty*SW + tx0 : aligned float4 LDS store, conflict-free
        *reinterpret_cast<float4*>(&sms[q * 4]) = r;
    }

    __syncthreads();

    // ---- phase 2: 9-neighbor aggregation, dilations 2 (narrow) & 4 (wide)
    const float* offb = offset + (size_t)b * 18 * HW;
    const float* wtb  = weight + (size_t)b * HW;
    float* outb = out + (size_t)(b * Dc + d) * HW;

#pragma unroll 1
    for (int k = 0; k < 5; ++k) {           // 5*256 = 1280 = TH*TW exactly
        const int idx = k * 256 + tid;
        const int oy  = idx / TW;
        const int ox  = idx - oy * TW;
        const int hw  = (h0t + oy) * Wc + (w0t + ox);

        float off[18];
#pragma unroll
        for (int s = 0; s < 18; ++s)
            off[s] = offb[s * HW + hw];
        const float wt = wtb[hw] * 0.5f;

        const float* sp = sms + (oy + R) * SW + (ox + R);
        float a = 0.f;
#pragma unroll
        for (int s = 0; s < 9; ++s) {
            const int dy = s / 3 - 1, dx = s % 3 - 1;
            a = fmaf(off[s + 9], sp[(dy * 2) * SW + dx * 2],
                fmaf(off[s],     sp[(dy * 4) * SW + dx * 4], a));
        }
        outb[hw] = a * wt;
    }
}

extern "C" void kernel_launch(void* const* d_in, const int* in_sizes, int n_in,
                              void* d_out, int out_size, void* d_ws, size_t ws_size,
                              hipStream_t stream)
{
    const float* x1     = (const float*)d_in[0];
    const float* offset = (const float*)d_in[1];
    const float* weight = (const float*)d_in[2];
    const float* w0     = (const float*)d_in[3];
    const float* s0     = (const float*)d_in[4];
    const float* b0     = (const float*)d_in[5];
    const float* w1     = (const float*)d_in[6];
    const float* s1     = (const float*)d_in[7];
    const float* b1     = (const float*)d_in[8];
    const float* wsim   = (const float*)d_in[9];
    const float* bsim   = (const float*)d_in[10];
    float* out = (float*)d_out;

    // B(2) * 16 tiles * D(32) = 1024 blocks, one fused pass, no workspace
    fused_kernel<<<1024, 256, 0, stream>>>(x1, offset, weight,
                                           w0, s0, b0, w1, s1, b1, wsim, bsim,
                                           out);
}

// Round 3
// 145.472 us; speedup vs baseline: 3.2107x; 3.2107x over previous
//
#include <hip/hip_runtime.h>

#define Bc 2
#define Gc 8
#define Dc 32
#define Hc 128
#define Wc 160
#define HW (Hc * Wc)         // 20480
#define DHW (Dc * HW)        // 655360

// Fused tiling: one block = one (b, d, 32x40 output tile).
// sim computed with reflect halo R=4 into LDS, aggregation reads LDS only.
#define TH 32
#define TW 40
#define R  4
#define SH (TH + 2 * R)      // 40
#define SW (TW + 2 * R)      // 48
#define SIMN (SH * SW)       // 1920
#define NQ (SIMN / 4)        // 480 float4-quads
#define QPR (SW / 4)         // 12 quads per sim-tile row

// NOTE: no min-waves arg. Round-2 showed __launch_bounds__(256,3) clamps to
// 84 VGPR on this toolchain -> forced spill -> 1 GB scratch traffic.
// Register pressure is instead cut STRUCTURALLY: layer-0 outputs are consumed
// immediately by layer-1 accumulators (no h0[16] array -> peak live ~80 VGPR).
__global__ __launch_bounds__(256) void fused_kernel(
    const float* __restrict__ x1, const float* __restrict__ offset,
    const float* __restrict__ weight,
    const float* __restrict__ w0, const float* __restrict__ s0, const float* __restrict__ b0,
    const float* __restrict__ w1, const float* __restrict__ s1, const float* __restrict__ b1,
    const float* __restrict__ wsim, const float* __restrict__ bsim,
    float* __restrict__ out)
{
    __shared__ __align__(16) float sms[SIMN];  // sim tile with halo
    __shared__ float smw[289];                 // folded MLP weights
    const int tid = threadIdx.x;

    // stage BN-folded weights
    for (int i = tid; i < 289; i += 256) {
        float v;
        if (i < 128)      v = w0[i] * s0[i >> 3];                 // w0f[o][g]
        else if (i < 144) v = b0[i - 128];
        else if (i < 272) v = w1[i - 144] * s1[(i - 144) >> 4];   // w1f[c][o]
        else if (i < 280) v = b1[i - 272];
        else if (i < 288) v = wsim[i - 280];
        else              v = bsim[0];
        smw[i] = v;
    }

    // blk = b*512 + tile*32 + d  (d innermost: consecutive blocks share the
    // offset/weight tile in L2; tile-neighbors are +32/+128 blocks = same XCD)
    const int blk = blockIdx.x;              // 1024 blocks
    const int d   = blk & 31;
    const int t   = (blk >> 5) & 15;
    const int b   = blk >> 9;
    const int h0t = (t >> 2) * TH;
    const int w0t = (t & 3) * TW;

    __syncthreads();

    const float* sw0 = smw;
    const float* sb0 = smw + 128;
    const float* sw1 = smw + 144;
    const float* sb1 = smw + 272;
    const float* sws = smw + 280;
    const float  sbs = smw[288];

    const float* xb = x1 + (size_t)b * (Gc * DHW) + (size_t)d * HW;

    // ---- phase 1: MLP 8->16->8->1 into the LDS sim tile (incl. reflect halo)
#pragma unroll 1
    for (int q = tid; q < NQ; q += 256) {
        const int ty  = q / QPR;
        const int tx0 = (q - ty * QPR) * 4;
        int gh = h0t - R + ty;
        gh = gh < 0 ? -gh : (gh >= Hc ? 2 * Hc - 2 - gh : gh);
        const int gw0 = w0t - R + tx0;

        float4 xv[Gc];
        if (gw0 >= 0 && gw0 <= Wc - 4) {
            // fast path: contiguous, 16B-aligned (w0t,tx0 multiples of 4)
            const float* p = xb + gh * Wc + gw0;
#pragma unroll
            for (int g = 0; g < Gc; ++g)
                xv[g] = *reinterpret_cast<const float4*>(p + g * DHW);
        } else {
            // reflected (reversed) edge quad: 4 scalar gathers per g
            int gw[4];
#pragma unroll
            for (int j = 0; j < 4; ++j) {
                int x = gw0 + j;
                gw[j] = x < 0 ? -x : (x >= Wc ? 2 * Wc - 2 - x : x);
            }
            const float* p = xb + gh * Wc;
#pragma unroll
            for (int g = 0; g < Gc; ++g) {
                xv[g].x = p[g * DHW + gw[0]];
                xv[g].y = p[g * DHW + gw[1]];
                xv[g].z = p[g * DHW + gw[2]];
                xv[g].w = p[g * DHW + gw[3]];
            }
        }

        // layer-1 accumulators, seeded with bias1 (8 x float4 = 32 regs)
        float4 acc1[8];
#pragma unroll
        for (int c = 0; c < 8; ++c) {
            const float bb = sb1[c];
            acc1[c].x = bb; acc1[c].y = bb; acc1[c].z = bb; acc1[c].w = bb;
        }

        // layer 0 fused into layer 1: each h0[o] is consumed immediately,
        // never materialized as an array -> no 64-reg h0 live set.
#pragma unroll
        for (int o = 0; o < 16; ++o) {
            float ax = sb0[o], ay = ax, az = ax, aw = ax;
#pragma unroll
            for (int g = 0; g < Gc; ++g) {
                const float wv = sw0[o * Gc + g];
                ax = fmaf(wv, xv[g].x, ax);
                ay = fmaf(wv, xv[g].y, ay);
                az = fmaf(wv, xv[g].z, az);
                aw = fmaf(wv, xv[g].w, aw);
            }
            ax = fmaxf(ax, 0.f);
            ay = fmaxf(ay, 0.f);
            az = fmaxf(az, 0.f);
            aw = fmaxf(aw, 0.f);
#pragma unroll
            for (int c = 0; c < 8; ++c) {
                const float wv = sw1[c * 16 + o];
                acc1[c].x = fmaf(wv, ax, acc1[c].x);
                acc1[c].y = fmaf(wv, ay, acc1[c].y);
                acc1[c].z = fmaf(wv, az, acc1[c].z);
                acc1[c].w = fmaf(wv, aw, acc1[c].w);
            }
        }

        // sim projection 8 -> 1
        float sx = sbs, sy = sbs, sz = sbs, sw = sbs;
#pragma unroll
        for (int c = 0; c < 8; ++c) {
            const float ws = sws[c];
            sx = fmaf(ws, fmaxf(acc1[c].x, 0.f), sx);
            sy = fmaf(ws, fmaxf(acc1[c].y, 0.f), sy);
            sz = fmaf(ws, fmaxf(acc1[c].z, 0.f), sz);
            sw = fmaf(ws, fmaxf(acc1[c].w, 0.f), sw);
        }

        float4 r; r.x = sx; r.y = sy; r.z = sz; r.w = sw;
        // q*4 == ty*SW + tx0 : aligned float4 LDS store, conflict-free
        *reinterpret_cast<float4*>(&sms[q * 4]) = r;
    }

    __syncthreads();

    // ---- phase 2: 9-neighbor aggregation, dilations 2 (narrow) & 4 (wide)
    const float* offb = offset + (size_t)b * 18 * HW;
    const float* wtb  = weight + (size_t)b * HW;
    float* outb = out + (size_t)(b * Dc + d) * HW;

#pragma unroll 1
    for (int k = 0; k < 5; ++k) {           // 5*256 = 1280 = TH*TW exactly
        const int idx = k * 256 + tid;
        const int oy  = idx / TW;
        const int ox  = idx - oy * TW;
        const int hw  = (h0t + oy) * Wc + (w0t + ox);

        float off[18];
#pragma unroll
        for (int s = 0; s < 18; ++s)
            off[s] = offb[s * HW + hw];
        const float wt = wtb[hw] * 0.5f;

        const float* sp = sms + (oy + R) * SW + (ox + R);
        float a = 0.f;
#pragma unroll
        for (int s = 0; s < 9; ++s) {
            const int dy = s / 3 - 1, dx = s % 3 - 1;
            a = fmaf(off[s + 9], sp[(dy * 2) * SW + dx * 2],
                fmaf(off[s],     sp[(dy * 4) * SW + dx * 4], a));
        }
        outb[hw] = a * wt;
    }
}

extern "C" void kernel_launch(void* const* d_in, const int* in_sizes, int n_in,
                              void* d_out, int out_size, void* d_ws, size_t ws_size,
                              hipStream_t stream)
{
    const float* x1     = (const float*)d_in[0];
    const float* offset = (const float*)d_in[1];
    const float* weight = (const float*)d_in[2];
    const float* w0     = (const float*)d_in[3];
    const float* s0     = (const float*)d_in[4];
    const float* b0     = (const float*)d_in[5];
    const float* w1     = (const float*)d_in[6];
    const float* s1     = (const float*)d_in[7];
    const float* b1     = (const float*)d_in[8];
    const float* wsim   = (const float*)d_in[9];
    const float* bsim   = (const float*)d_in[10];
    float* out = (float*)d_out;

    // B(2) * 16 tiles * D(32) = 1024 blocks, one fused pass, no workspace
    fused_kernel<<<1024, 256, 0, stream>>>(x1, offset, weight,
                                           w0, s0, b0, w1, s1, b1, wsim, bsim,
                                           out);
}